// Round 3
// baseline (297.298 us; speedup 1.0000x reference)
//
#include <hip/hip_runtime.h>

#define NE 8
#define CAP 1024
#define HD 1024
#define ID 1408
#define TT 2048

typedef __attribute__((ext_vector_type(8))) short bf16x8;
typedef __attribute__((ext_vector_type(4))) float f32x4;
typedef unsigned short u16;
typedef unsigned int u32;
typedef unsigned long long u64;

__device__ __forceinline__ u16 f2bf(float f) {
  u32 u = __float_as_uint(f);
  u = (u + 0x7fffu + ((u >> 16) & 1u)) >> 16;
  return (u16)u;
}
__device__ __forceinline__ float bf2f(u16 b) {
  return __uint_as_float(((u32)b) << 16);
}

__device__ __forceinline__ void async_cp16(const void* g, void* l) {
  __builtin_amdgcn_global_load_lds(
      (const __attribute__((address_space(1))) u32*)g,
      (__attribute__((address_space(3))) u32*)l, 16, 0, 0);
}

// ---------------- fp32 -> bf16 convert ----------------
__global__ void cvt_kernel(const float4* __restrict__ src, ushort4* __restrict__ dst, int n4) {
  int i = blockIdx.x * 256 + threadIdx.x;
  if (i >= n4) return;
  float4 v = src[i];
  ushort4 o;
  o.x = f2bf(v.x); o.y = f2bf(v.y); o.z = f2bf(v.z); o.w = f2bf(v.w);
  dst[i] = o;
}

// ---------------- routing: exact flat-order cumsum positions ----------------
__global__ void route_kernel(const int* __restrict__ ids, int* __restrict__ rowmap,
                             int* __restrict__ flatpos, int* __restrict__ counts) {
  __shared__ int ids_s[TT * 2];
  __shared__ int sc[256][NE + 1];
  int tid = threadIdx.x;
  for (int i = tid; i < TT * 2; i += 256) ids_s[i] = ids[i];
  __syncthreads();
  int base = tid * 16;
  u64 own64 = 0;
#pragma unroll
  for (int j = 0; j < 16; ++j) own64 += 1ull << (ids_s[base + j] * 8);
  int own[NE];
#pragma unroll
  for (int e = 0; e < NE; ++e) { own[e] = (int)((own64 >> (e * 8)) & 0xff); sc[tid][e] = own[e]; }
  __syncthreads();
  for (int off = 1; off < 256; off <<= 1) {
    int v[NE];
    if (tid >= off) {
#pragma unroll
      for (int e = 0; e < NE; ++e) v[e] = sc[tid - off][e];
    }
    __syncthreads();
    if (tid >= off) {
#pragma unroll
      for (int e = 0; e < NE; ++e) sc[tid][e] += v[e];
    }
    __syncthreads();
  }
  if (tid == 255) {
#pragma unroll
    for (int e = 0; e < NE; ++e) counts[e] = sc[255][e] < CAP ? sc[255][e] : CAP;
  }
  int excl[NE];
#pragma unroll
  for (int e = 0; e < NE; ++e) excl[e] = sc[tid][e] - own[e];
  __syncthreads();
#pragma unroll
  for (int e = 0; e < NE; ++e) sc[tid][e] = excl[e];
#pragma unroll
  for (int j = 0; j < 16; ++j) {
    int f = base + j;
    int e = ids_s[f];
    int p = sc[tid][e]++;
    if (p < CAP) { rowmap[e * CAP + p] = f; flatpos[f] = p; }
    else flatpos[f] = -1;
  }
}

// ---------------- bf16 BT GEMM, double-buffered pipelined K-loop ----------------
// C[m,n] = sum_k A[m,k]*B[n,k]. 128x128 tile, BK=64, 4 waves (2x2 of 64x64),
// 16x16x32 MFMA, global_load_lds width=16, XOR chunk swizzle.
// Pipeline: 2 LDS buffers; prefetch tile kt+1 issued before waiting on tile kt;
// raw s_barrier + manual s_waitcnt vmcnt(8) keeps 8 loads in flight across the
// barrier (HIP __syncthreads would force vmcnt(0) drain). Last iter peeled.
// XCD swizzle: gridDim.x == 8 -> linear id % 8 == expert -> each XCD owns one
// expert, B re-reads hit its L2 (R2: FETCH 111->28 MB).
template <bool GATHER>
__global__ __launch_bounds__(256) void gemm_bt(
    const u16* __restrict__ A, const u16* __restrict__ B, u16* __restrict__ C,
    const int* __restrict__ rowmap, const int* __restrict__ counts,
    int KE, int Astride, long long Bexp, int Cstride) {
  int e = blockIdx.x;
  int count = counts[e];
  int m0 = blockIdx.y * 128;
  if (m0 >= count) return;
  int n0 = blockIdx.z * 128;
  int tid = threadIdx.x;
  int lane = tid & 63, wid = tid >> 6;
  int wm = wid >> 1, wn = wid & 1;
  int q = lane >> 4, lm = lane & 15;

  __shared__ __align__(16) char smA[2][128 * 128];
  __shared__ __align__(16) char smB[2][128 * 128];

  int rloc = tid >> 3;
  int chs = ((tid & 7) ^ (rloc & 7)) * 8;  // swizzled elem offset in 64-elem k-tile
  const u16* aP[4];
  const u16* bP[4];
#pragma unroll
  for (int i = 0; i < 4; ++i) {
    int row = rloc + 32 * i;
    if (GATHER) {
      int gr = m0 + row;
      int f = (gr < count) ? rowmap[e * CAP + gr] : 0;
      aP[i] = A + (size_t)(f >> 1) * Astride + chs;  // token = f/2 (K_top=2)
    } else {
      aP[i] = A + ((size_t)e * CAP + m0 + row) * Astride + chs;
    }
    bP[i] = B + (size_t)e * Bexp + (size_t)(n0 + row) * KE + chs;
  }

  f32x4 zero = {0.f, 0.f, 0.f, 0.f};
  f32x4 acc[4][4];
#pragma unroll
  for (int mi = 0; mi < 4; ++mi)
#pragma unroll
    for (int ni = 0; ni < 4; ++ni) acc[mi][ni] = zero;

  int nkt = KE >> 6;

  auto stage = [&](int kt, int buf) {
    int ko = kt * 64;
#pragma unroll
    for (int i = 0; i < 4; ++i) {
      async_cp16(aP[i] + ko, smA[buf] + (i * 256 + tid) * 16);
      async_cp16(bP[i] + ko, smB[buf] + (i * 256 + tid) * 16);
    }
  };

  auto compute = [&](int buf) {
#pragma unroll
    for (int s = 0; s < 2; ++s) {
      bf16x8 af[4], bfr[4];
#pragma unroll
      for (int mi = 0; mi < 4; ++mi) {
        int row = wm * 64 + mi * 16 + lm;
        af[mi] = *(const bf16x8*)(smA[buf] + row * 128 + (((s * 4 + q) ^ (lm & 7)) * 16));
      }
#pragma unroll
      for (int ni = 0; ni < 4; ++ni) {
        int row = wn * 64 + ni * 16 + lm;
        bfr[ni] = *(const bf16x8*)(smB[buf] + row * 128 + (((s * 4 + q) ^ (lm & 7)) * 16));
      }
#pragma unroll
      for (int mi = 0; mi < 4; ++mi)
#pragma unroll
        for (int ni = 0; ni < 4; ++ni)
          acc[mi][ni] = __builtin_amdgcn_mfma_f32_16x16x32_bf16(af[mi], bfr[ni], acc[mi][ni], 0, 0, 0);
    }
  };

  stage(0, 0);
  if (nkt > 1) stage(1, 1);
  for (int kt = 0; kt < nkt - 1; ++kt) {
    // tile kt's 8 loads are the oldest; tile kt+1's 8 stay in flight
    asm volatile("s_waitcnt vmcnt(8)" ::: "memory");
    asm volatile("s_barrier" ::: "memory");
    compute(kt & 1);
    asm volatile("s_waitcnt lgkmcnt(0)" ::: "memory");
    asm volatile("s_barrier" ::: "memory");  // all waves done reading buf kt&1
    if (kt + 2 < nkt) stage(kt + 2, kt & 1);
  }
  asm volatile("s_waitcnt vmcnt(0)" ::: "memory");
  asm volatile("s_barrier" ::: "memory");
  compute((nkt - 1) & 1);

  // epilogue: C/D layout col=lane&15, row=quad*4+reg (m89-verified)
#pragma unroll
  for (int mi = 0; mi < 4; ++mi) {
#pragma unroll
    for (int ni = 0; ni < 4; ++ni) {
      int col = n0 + wn * 64 + ni * 16 + lm;
#pragma unroll
      for (int r = 0; r < 4; ++r) {
        int row = m0 + wm * 64 + mi * 16 + q * 4 + r;
        C[((size_t)e * CAP + row) * Cstride + col] = f2bf(acc[mi][ni][r]);
      }
    }
  }
}

// ---------------- SiLU(gate)*up, in-place into gate half of h ----------------
struct alignas(16) us8 { u16 v[8]; };
__global__ void act_kernel(u16* __restrict__ h, const int* __restrict__ counts) {
  int e = blockIdx.y;
  int c = blockIdx.x;
  if (c >= counts[e]) return;
  int tid = threadIdx.x;
  if (tid >= ID / 8) return;
  u16* rowp = h + ((size_t)e * CAP + c) * (2 * ID);
  us8 g = *(const us8*)(rowp + tid * 8);
  us8 u = *(const us8*)(rowp + ID + tid * 8);
  us8 o;
#pragma unroll
  for (int j = 0; j < 8; ++j) {
    float gf = bf2f(g.v[j]);
    float uf = bf2f(u.v[j]);
    float a = gf / (1.f + __expf(-gf)) * uf;
    o.v[j] = f2bf(a);
  }
  *(us8*)(rowp + tid * 8) = o;
}

// ---------------- per-token weighted combine (fully overwrites out) ----------------
__global__ void combine_kernel(const float* __restrict__ tw, const int* __restrict__ ids,
                               const int* __restrict__ flatpos, const u16* __restrict__ y,
                               float* __restrict__ out) {
  int t = blockIdx.x;
  int tid = threadIdx.x;
  int h0 = tid * 4;
  float a0 = 0.f, a1 = 0.f, a2 = 0.f, a3 = 0.f;
#pragma unroll
  for (int k = 0; k < 2; ++k) {
    int f = t * 2 + k;
    int p = flatpos[f];
    if (p >= 0) {
      int e = ids[f];
      float w = tw[f];
      const u16* yr = y + ((size_t)e * CAP + p) * HD + h0;
      ushort4 v = *(const ushort4*)yr;
      a0 += w * bf2f(v.x);
      a1 += w * bf2f(v.y);
      a2 += w * bf2f(v.z);
      a3 += w * bf2f(v.w);
    }
  }
  float4 o = {a0, a1, a2, a3};
  *(float4*)(out + (size_t)t * HD + h0) = o;
}

extern "C" void kernel_launch(void* const* d_in, const int* in_sizes, int n_in,
                              void* d_out, int out_size, void* d_ws, size_t ws_size,
                              hipStream_t stream) {
  const float* hidden = (const float*)d_in[0];
  const float* w1 = (const float*)d_in[1];
  const float* w2 = (const float*)d_in[2];
  const float* tw = (const float*)d_in[3];
  const int* ids = (const int*)d_in[4];
  float* out = (float*)d_out;

  char* p = (char*)d_ws;
  auto alloc = [&](size_t b) { char* r = p; p += (b + 255) & ~(size_t)255; return r; };
  u16* bw1 = (u16*)alloc((size_t)NE * 2 * ID * HD * 2);   // 46.1 MB
  u16* bw2 = (u16*)alloc((size_t)NE * HD * ID * 2);        // 23.1 MB
  u16* bx = (u16*)alloc((size_t)TT * HD * 2);              // 4.2 MB
  u16* hbuf = (u16*)alloc((size_t)NE * CAP * 2 * ID * 2);  // 46.1 MB
  u16* ybuf = (u16*)alloc((size_t)NE * CAP * HD * 2);      // 16.8 MB
  int* rowmap = (int*)alloc((size_t)NE * CAP * 4);
  int* flatpos = (int*)alloc((size_t)TT * 2 * 4);
  int* counts = (int*)alloc((size_t)NE * 4);

  int n4w1 = NE * 2 * ID * HD / 4;
  cvt_kernel<<<(n4w1 + 255) / 256, 256, 0, stream>>>((const float4*)w1, (ushort4*)bw1, n4w1);
  int n4w2 = NE * HD * ID / 4;
  cvt_kernel<<<(n4w2 + 255) / 256, 256, 0, stream>>>((const float4*)w2, (ushort4*)bw2, n4w2);
  int n4x = TT * HD / 4;
  cvt_kernel<<<(n4x + 255) / 256, 256, 0, stream>>>((const float4*)hidden, (ushort4*)bx, n4x);

  route_kernel<<<1, 256, 0, stream>>>(ids, rowmap, flatpos, counts);

  // GEMM1: h[e, c, 0:2816] = x_gathered[c, :1024] . w1[e, n, :1024]^T
  gemm_bt<true><<<dim3(NE, CAP / 128, 2 * ID / 128), 256, 0, stream>>>(
      bx, bw1, hbuf, rowmap, counts, HD, HD, (long long)2 * ID * HD, 2 * ID);

  act_kernel<<<dim3(CAP, NE), 256, 0, stream>>>(hbuf, counts);

  // GEMM2: y[e, c, 0:1024] = act[c, :1408] . w2[e, n, :1408]^T  (act = gate half of hbuf, stride 2816)
  gemm_bt<false><<<dim3(NE, CAP / 128, HD / 128), 256, 0, stream>>>(
      hbuf, bw2, ybuf, rowmap, counts, ID, 2 * ID, (long long)HD * ID, HD);

  combine_kernel<<<TT, 256, 0, stream>>>(tw, ids, flatpos, ybuf, out);
}

// Round 5
// 292.260 us; speedup vs baseline: 1.0172x; 1.0172x over previous
//
#include <hip/hip_runtime.h>

#define NE 8
#define CAP 1024
#define HD 1024
#define ID 1408
#define TT 2048

typedef __attribute__((ext_vector_type(8))) short bf16x8;
typedef __attribute__((ext_vector_type(4))) float f32x4;
typedef unsigned short u16;
typedef unsigned int u32;
typedef unsigned long long u64;

__device__ __forceinline__ u16 f2bf(float f) {
  u32 u = __float_as_uint(f);
  u = (u + 0x7fffu + ((u >> 16) & 1u)) >> 16;
  return (u16)u;
}
__device__ __forceinline__ float bf2f(u16 b) {
  return __uint_as_float(((u32)b) << 16);
}

__device__ __forceinline__ void async_cp16(const void* g, void* l) {
  __builtin_amdgcn_global_load_lds(
      (const __attribute__((address_space(1))) u32*)g,
      (__attribute__((address_space(3))) u32*)l, 16, 0, 0);
}

// ---------------- fp32 -> bf16 convert (flat) ----------------
__global__ void cvt_kernel(const float4* __restrict__ src, ushort4* __restrict__ dst, int n4) {
  int i = blockIdx.x * 256 + threadIdx.x;
  if (i >= n4) return;
  float4 v = src[i];
  ushort4 o;
  o.x = f2bf(v.x); o.y = f2bf(v.y); o.z = f2bf(v.z); o.w = f2bf(v.w);
  dst[i] = o;
}

// ---------------- w1 cvt with gate/up row interleave ----------------
// src row n (0..1407 = gate_n, 1408..2815 = up_{n-1408})
// dst row n' : gate_j -> 2j, up_j -> 2j+1. One block per (row, expert).
__global__ void cvt_w1_kernel(const float4* __restrict__ src, ushort4* __restrict__ dst) {
  int n = blockIdx.x;           // 0..2815
  int e = blockIdx.y;           // 0..7
  int tid = threadIdx.x;        // 0..255, one float4 each (H=1024)
  int np = (n < ID) ? (2 * n) : (2 * (n - ID) + 1);
  float4 v = src[((size_t)e * 2 * ID + n) * (HD / 4) + tid];
  ushort4 o;
  o.x = f2bf(v.x); o.y = f2bf(v.y); o.z = f2bf(v.z); o.w = f2bf(v.w);
  dst[((size_t)e * 2 * ID + np) * (HD / 4) + tid] = o;
}

// ---------------- zero d_out (harness poisons it to 0xAA) ----------------
__global__ void zero_kernel(float4* __restrict__ out, int n4) {
  int i = blockIdx.x * 256 + threadIdx.x;
  if (i < n4) out[i] = float4{0.f, 0.f, 0.f, 0.f};
}

// ---------------- routing: exact flat-order cumsum positions ----------------
__global__ void route_kernel(const int* __restrict__ ids, int* __restrict__ rowmap,
                             int* __restrict__ flatpos, int* __restrict__ counts) {
  __shared__ int ids_s[TT * 2];
  __shared__ int sc[256][NE + 1];
  int tid = threadIdx.x;
  for (int i = tid; i < TT * 2; i += 256) ids_s[i] = ids[i];
  __syncthreads();
  int base = tid * 16;
  u64 own64 = 0;
#pragma unroll
  for (int j = 0; j < 16; ++j) own64 += 1ull << (ids_s[base + j] * 8);
  int own[NE];
#pragma unroll
  for (int e = 0; e < NE; ++e) { own[e] = (int)((own64 >> (e * 8)) & 0xff); sc[tid][e] = own[e]; }
  __syncthreads();
  for (int off = 1; off < 256; off <<= 1) {
    int v[NE];
    if (tid >= off) {
#pragma unroll
      for (int e = 0; e < NE; ++e) v[e] = sc[tid - off][e];
    }
    __syncthreads();
    if (tid >= off) {
#pragma unroll
      for (int e = 0; e < NE; ++e) sc[tid][e] += v[e];
    }
    __syncthreads();
  }
  if (tid == 255) {
#pragma unroll
    for (int e = 0; e < NE; ++e) counts[e] = sc[255][e] < CAP ? sc[255][e] : CAP;
  }
  int excl[NE];
#pragma unroll
  for (int e = 0; e < NE; ++e) excl[e] = sc[tid][e] - own[e];
  __syncthreads();
#pragma unroll
  for (int e = 0; e < NE; ++e) sc[tid][e] = excl[e];
#pragma unroll
  for (int j = 0; j < 16; ++j) {
    int f = base + j;
    int e = ids_s[f];
    int p = sc[tid][e]++;
    if (p < CAP) { rowmap[e * CAP + p] = f; flatpos[f] = p; }
    else flatpos[f] = -1;
  }
}

// ---------------- GEMM1: gathered x . w1_interleaved^T, fused SiLU ----------------
// 128x128 tile, BK=64, 4 waves (2x2 of 64x64), single-buffer K-loop (R2-proven).
// B rows interleaved: tile col 2c = gate, 2c+1 = up (adjacent lanes in MFMA C/D).
// Epilogue: u = __shfl_xor(v,1); even lanes compute silu(g)*u, store 1 col each.
// XCD swizzle: gridDim.x == 8 -> lin%8 == expert -> per-XCD L2 holds one expert.
__global__ __launch_bounds__(256) void gemm1_kernel(
    const u16* __restrict__ A, const u16* __restrict__ B, u16* __restrict__ Hb,
    const int* __restrict__ rowmap, const int* __restrict__ counts) {
  int e = blockIdx.x;
  int count = counts[e];
  int m0 = blockIdx.y * 128;
  if (m0 >= count) return;
  int n0 = blockIdx.z * 128;
  int tid = threadIdx.x;
  int lane = tid & 63, wid = tid >> 6;
  int wm = wid >> 1, wn = wid & 1;
  int q = lane >> 4, lm = lane & 15;

  __shared__ __align__(16) char smA[128 * 128];
  __shared__ __align__(16) char smB[128 * 128];

  int rloc = tid >> 3;
  int chs = ((tid & 7) ^ (rloc & 7)) * 8;
  const u16* aP[4];
  const u16* bP[4];
#pragma unroll
  for (int i = 0; i < 4; ++i) {
    int row = rloc + 32 * i;
    int gr = m0 + row;
    int f = (gr < count) ? rowmap[e * CAP + gr] : 0;
    aP[i] = A + (size_t)(f >> 1) * HD + chs;
    bP[i] = B + ((size_t)e * 2 * ID + n0 + row) * HD + chs;
  }

  f32x4 zero = {0.f, 0.f, 0.f, 0.f};
  f32x4 acc[4][4];
#pragma unroll
  for (int mi = 0; mi < 4; ++mi)
#pragma unroll
    for (int ni = 0; ni < 4; ++ni) acc[mi][ni] = zero;

  for (int kt = 0; kt < HD / 64; ++kt) {
    int ko = kt * 64;
#pragma unroll
    for (int i = 0; i < 4; ++i) {
      async_cp16(aP[i] + ko, smA + (i * 256 + tid) * 16);
      async_cp16(bP[i] + ko, smB + (i * 256 + tid) * 16);
    }
    asm volatile("s_waitcnt vmcnt(0)" ::: "memory");
    __syncthreads();
#pragma unroll
    for (int s = 0; s < 2; ++s) {
      bf16x8 af[4], bfr[4];
#pragma unroll
      for (int mi = 0; mi < 4; ++mi) {
        int row = wm * 64 + mi * 16 + lm;
        af[mi] = *(const bf16x8*)(smA + row * 128 + (((s * 4 + q) ^ (lm & 7)) * 16));
      }
#pragma unroll
      for (int ni = 0; ni < 4; ++ni) {
        int row = wn * 64 + ni * 16 + lm;
        bfr[ni] = *(const bf16x8*)(smB + row * 128 + (((s * 4 + q) ^ (lm & 7)) * 16));
      }
#pragma unroll
      for (int mi = 0; mi < 4; ++mi)
#pragma unroll
        for (int ni = 0; ni < 4; ++ni)
          acc[mi][ni] = __builtin_amdgcn_mfma_f32_16x16x32_bf16(af[mi], bfr[ni], acc[mi][ni], 0, 0, 0);
    }
    __syncthreads();
  }

  // fused SiLU epilogue. col-in-tile = wn*64+ni*16+lm; even = gate, odd = up.
  bool isGate = (lm & 1) == 0;
#pragma unroll
  for (int mi = 0; mi < 4; ++mi) {
#pragma unroll
    for (int ni = 0; ni < 4; ++ni) {
      int cOut = (n0 >> 1) + wn * 32 + ni * 8 + (lm >> 1);
#pragma unroll
      for (int r = 0; r < 4; ++r) {
        float v = acc[mi][ni][r];
        float partner = __shfl_xor(v, 1, 64);
        if (isGate) {
          float g = v, u = partner;
          float a = g / (1.f + __expf(-g)) * u;
          int row = m0 + wm * 64 + mi * 16 + q * 4 + r;
          Hb[((size_t)e * CAP + row) * ID + cOut] = f2bf(a);
        }
      }
    }
  }
}

// ---------------- GEMM2: act . w2^T, fused weighted combine (atomicAdd) ----------
// 64x128 tile (2 blocks/CU), BK=64, 4 waves (2x2 of 32x64), single-buffer K-loop.
__global__ __launch_bounds__(256) void gemm2_kernel(
    const u16* __restrict__ A, const u16* __restrict__ B, float* __restrict__ out,
    const int* __restrict__ rowmap, const int* __restrict__ counts,
    const float* __restrict__ tw) {
  int e = blockIdx.x;
  int count = counts[e];
  int m0 = blockIdx.y * 64;
  if (m0 >= count) return;
  int n0 = blockIdx.z * 128;
  int tid = threadIdx.x;
  int lane = tid & 63, wid = tid >> 6;
  int wm = wid >> 1, wn = wid & 1;
  int q = lane >> 4, lm = lane & 15;

  __shared__ __align__(16) char smA[64 * 128];
  __shared__ __align__(16) char smB[128 * 128];

  int rloc = tid >> 3;
  int chs = ((tid & 7) ^ (rloc & 7)) * 8;
  const u16* aP[2];
  const u16* bP[4];
#pragma unroll
  for (int i = 0; i < 2; ++i)
    aP[i] = A + ((size_t)e * CAP + m0 + rloc + 32 * i) * ID + chs;
#pragma unroll
  for (int i = 0; i < 4; ++i)
    bP[i] = B + ((size_t)e * HD + n0 + rloc + 32 * i) * ID + chs;

  f32x4 zero = {0.f, 0.f, 0.f, 0.f};
  f32x4 acc[2][4];
#pragma unroll
  for (int mi = 0; mi < 2; ++mi)
#pragma unroll
    for (int ni = 0; ni < 4; ++ni) acc[mi][ni] = zero;

  for (int kt = 0; kt < ID / 64; ++kt) {
    int ko = kt * 64;
#pragma unroll
    for (int i = 0; i < 2; ++i)
      async_cp16(aP[i] + ko, smA + (i * 256 + tid) * 16);
#pragma unroll
    for (int i = 0; i < 4; ++i)
      async_cp16(bP[i] + ko, smB + (i * 256 + tid) * 16);
    asm volatile("s_waitcnt vmcnt(0)" ::: "memory");
    __syncthreads();
#pragma unroll
    for (int s = 0; s < 2; ++s) {
      bf16x8 af[2], bfr[4];
#pragma unroll
      for (int mi = 0; mi < 2; ++mi) {
        int row = wm * 32 + mi * 16 + lm;
        af[mi] = *(const bf16x8*)(smA + row * 128 + (((s * 4 + q) ^ (lm & 7)) * 16));
      }
#pragma unroll
      for (int ni = 0; ni < 4; ++ni) {
        int row = wn * 64 + ni * 16 + lm;
        bfr[ni] = *(const bf16x8*)(smB + row * 128 + (((s * 4 + q) ^ (lm & 7)) * 16));
      }
#pragma unroll
      for (int mi = 0; mi < 2; ++mi)
#pragma unroll
        for (int ni = 0; ni < 4; ++ni)
          acc[mi][ni] = __builtin_amdgcn_mfma_f32_16x16x32_bf16(af[mi], bfr[ni], acc[mi][ni], 0, 0, 0);
    }
    __syncthreads();
  }

  // fused combine epilogue: out[token, col] += w * y
#pragma unroll
  for (int mi = 0; mi < 2; ++mi) {
#pragma unroll
    for (int r = 0; r < 4; ++r) {
      int grow = m0 + wm * 32 + mi * 16 + q * 4 + r;
      if (grow < count) {
        int f = rowmap[e * CAP + grow];
        float w = tw[f];
        int t = f >> 1;
#pragma unroll
        for (int ni = 0; ni < 4; ++ni) {
          int col = n0 + wn * 64 + ni * 16 + lm;
          atomicAdd(&out[(size_t)t * HD + col], w * acc[mi][ni][r]);
        }
      }
    }
  }
}

extern "C" void kernel_launch(void* const* d_in, const int* in_sizes, int n_in,
                              void* d_out, int out_size, void* d_ws, size_t ws_size,
                              hipStream_t stream) {
  const float* hidden = (const float*)d_in[0];
  const float* w1 = (const float*)d_in[1];
  const float* w2 = (const float*)d_in[2];
  const float* tw = (const float*)d_in[3];
  const int* ids = (const int*)d_in[4];
  float* out = (float*)d_out;

  char* p = (char*)d_ws;
  auto alloc = [&](size_t b) { char* r = p; p += (b + 255) & ~(size_t)255; return r; };
  u16* bw1 = (u16*)alloc((size_t)NE * 2 * ID * HD * 2);   // 46.1 MB (interleaved rows)
  u16* bw2 = (u16*)alloc((size_t)NE * HD * ID * 2);        // 23.1 MB
  u16* bx = (u16*)alloc((size_t)TT * HD * 2);              // 4.2 MB
  u16* hbuf = (u16*)alloc((size_t)NE * CAP * ID * 2);      // 23.1 MB (act only)
  int* rowmap = (int*)alloc((size_t)NE * CAP * 4);
  int* flatpos = (int*)alloc((size_t)TT * 2 * 4);
  int* counts = (int*)alloc((size_t)NE * 4);

  cvt_w1_kernel<<<dim3(2 * ID, NE), 256, 0, stream>>>((const float4*)w1, (ushort4*)bw1);
  int n4w2 = NE * HD * ID / 4;
  cvt_kernel<<<(n4w2 + 255) / 256, 256, 0, stream>>>((const float4*)w2, (ushort4*)bw2, n4w2);
  int n4x = TT * HD / 4;
  cvt_kernel<<<(n4x + 255) / 256, 256, 0, stream>>>((const float4*)hidden, (ushort4*)bx, n4x);

  route_kernel<<<1, 256, 0, stream>>>(ids, rowmap, flatpos, counts);

  int n4o = TT * HD / 4;
  zero_kernel<<<(n4o + 255) / 256, 256, 0, stream>>>((float4*)out, n4o);

  // GEMM1 + SiLU: hbuf[e,c,0:1408] = silu(x.w1g^T) * (x.w1u^T)
  gemm1_kernel<<<dim3(NE, CAP / 128, 2 * ID / 128), 256, 0, stream>>>(
      bx, bw1, hbuf, rowmap, counts);

  // GEMM2 + combine: out[t,:] += w * (act . w2^T)
  gemm2_kernel<<<dim3(NE, CAP / 64, HD / 128), 256, 0, stream>>>(
      hbuf, bw2, out, rowmap, counts, tw);
}

// Round 7
// 271.258 us; speedup vs baseline: 1.0960x; 1.0774x over previous
//
#include <hip/hip_runtime.h>

#define NE 8
#define CAP 1024
#define HD 1024
#define ID 1408
#define TT 2048

typedef __attribute__((ext_vector_type(8))) short bf16x8;
typedef __attribute__((ext_vector_type(4))) float f32x4;
typedef unsigned short u16;
typedef unsigned int u32;
typedef unsigned long long u64;

__device__ __forceinline__ u16 f2bf(float f) {
  u32 u = __float_as_uint(f);
  u = (u + 0x7fffu + ((u >> 16) & 1u)) >> 16;
  return (u16)u;
}
__device__ __forceinline__ float bf2f(u16 b) {
  return __uint_as_float(((u32)b) << 16);
}

__device__ __forceinline__ void async_cp16(const void* g, void* l) {
  __builtin_amdgcn_global_load_lds(
      (const __attribute__((address_space(1))) u32*)g,
      (__attribute__((address_space(3))) u32*)l, 16, 0, 0);
}

// ---------------- fp32 -> bf16 convert (flat) ----------------
__global__ void cvt_kernel(const float4* __restrict__ src, ushort4* __restrict__ dst, int n4) {
  int i = blockIdx.x * 256 + threadIdx.x;
  if (i >= n4) return;
  float4 v = src[i];
  ushort4 o;
  o.x = f2bf(v.x); o.y = f2bf(v.y); o.z = f2bf(v.z); o.w = f2bf(v.w);
  dst[i] = o;
}

// ---------------- w1 cvt with group-16 gate/up interleave ----------------
// gate j -> row (j>>4)*32 + (j&15); up j -> (j>>4)*32 + 16 + (j&15).
// In a 128-col B-tile this makes acc[ni even]=gate, acc[ni odd]=up for the
// SAME 16 outputs in the SAME lane -> silu merge needs no cross-lane traffic.
__global__ void cvt_w1_kernel(const float4* __restrict__ src, ushort4* __restrict__ dst) {
  int n = blockIdx.x;           // 0..2815
  int e = blockIdx.y;           // 0..7
  int tid = threadIdx.x;        // 0..255, one float4 each (H=1024)
  int j = (n < ID) ? n : (n - ID);
  int np = (j >> 4) * 32 + (j & 15) + ((n < ID) ? 0 : 16);
  float4 v = src[((size_t)e * 2 * ID + n) * (HD / 4) + tid];
  ushort4 o;
  o.x = f2bf(v.x); o.y = f2bf(v.y); o.z = f2bf(v.z); o.w = f2bf(v.w);
  dst[((size_t)e * 2 * ID + np) * (HD / 4) + tid] = o;
}

// ---------------- zero d_out (harness poisons it to 0xAA) ----------------
__global__ void zero_kernel(float4* __restrict__ out, int n4) {
  int i = blockIdx.x * 256 + threadIdx.x;
  if (i < n4) out[i] = float4{0.f, 0.f, 0.f, 0.f};
}

// ---------------- routing: exact flat-order cumsum positions ----------------
__global__ void route_kernel(const int* __restrict__ ids, int* __restrict__ rowmap,
                             int* __restrict__ flatpos, int* __restrict__ counts) {
  __shared__ int ids_s[TT * 2];
  __shared__ int sc[256][NE + 1];
  int tid = threadIdx.x;
  for (int i = tid; i < TT * 2; i += 256) ids_s[i] = ids[i];
  __syncthreads();
  int base = tid * 16;
  u64 own64 = 0;
#pragma unroll
  for (int j = 0; j < 16; ++j) own64 += 1ull << (ids_s[base + j] * 8);
  int own[NE];
#pragma unroll
  for (int e = 0; e < NE; ++e) { own[e] = (int)((own64 >> (e * 8)) & 0xff); sc[tid][e] = own[e]; }
  __syncthreads();
  for (int off = 1; off < 256; off <<= 1) {
    int v[NE];
    if (tid >= off) {
#pragma unroll
      for (int e = 0; e < NE; ++e) v[e] = sc[tid - off][e];
    }
    __syncthreads();
    if (tid >= off) {
#pragma unroll
      for (int e = 0; e < NE; ++e) sc[tid][e] += v[e];
    }
    __syncthreads();
  }
  if (tid == 255) {
#pragma unroll
    for (int e = 0; e < NE; ++e) counts[e] = sc[255][e] < CAP ? sc[255][e] : CAP;
  }
  int excl[NE];
#pragma unroll
  for (int e = 0; e < NE; ++e) excl[e] = sc[tid][e] - own[e];
  __syncthreads();
#pragma unroll
  for (int e = 0; e < NE; ++e) sc[tid][e] = excl[e];
#pragma unroll
  for (int j = 0; j < 16; ++j) {
    int f = base + j;
    int e = ids_s[f];
    int p = sc[tid][e]++;
    if (p < CAP) { rowmap[e * CAP + p] = f; flatpos[f] = p; }
    else flatpos[f] = -1;
  }
}

// ---------------- GEMM1: gathered x . w1_il^T, fused SiLU, 64x128 tile --------
// 4 waves (2x2 of 32x64), BK=64, single-buffer K-loop. ~1400 active blocks
// (5.5/CU) so inter-block overlap hides the per-tile vmcnt(0)+barrier drain.
// Epilogue: same-lane silu(gate)*up (ni even/odd pairs), LDS repack, 16B stores.
// R6 bug fixed: writeback now moves the FULL 16-u16 segment per thread
// (two bf16x8), not 8 — half the tile was left 0xAA-poisoned before.
__global__ __launch_bounds__(256) void gemm1_kernel(
    const u16* __restrict__ A, const u16* __restrict__ B, u16* __restrict__ Hb,
    const int* __restrict__ rowmap, const int* __restrict__ counts) {
  int e = blockIdx.x;
  int count = counts[e];
  int m0 = blockIdx.y * 64;
  if (m0 >= count) return;
  int n0 = blockIdx.z * 128;
  int tid = threadIdx.x;
  int lane = tid & 63, wid = tid >> 6;
  int wm = wid >> 1, wn = wid & 1;
  int q = lane >> 4, lm = lane & 15;

  __shared__ __align__(16) char smA[64 * 128];    // 8 KB
  __shared__ __align__(16) char smB[128 * 128];   // 16 KB

  int rloc = tid >> 3;
  int chs = ((tid & 7) ^ (rloc & 7)) * 8;
  const u16* aP[2];
  const u16* bP[4];
#pragma unroll
  for (int i = 0; i < 2; ++i) {
    int gr = m0 + rloc + 32 * i;
    int f = (gr < count) ? rowmap[e * CAP + gr] : 0;
    aP[i] = A + (size_t)(f >> 1) * HD + chs;
  }
#pragma unroll
  for (int i = 0; i < 4; ++i)
    bP[i] = B + ((size_t)e * 2 * ID + n0 + rloc + 32 * i) * HD + chs;

  f32x4 zero = {0.f, 0.f, 0.f, 0.f};
  f32x4 acc[2][4];
#pragma unroll
  for (int mi = 0; mi < 2; ++mi)
#pragma unroll
    for (int ni = 0; ni < 4; ++ni) acc[mi][ni] = zero;

  for (int kt = 0; kt < HD / 64; ++kt) {
    int ko = kt * 64;
#pragma unroll
    for (int i = 0; i < 2; ++i)
      async_cp16(aP[i] + ko, smA + (i * 256 + tid) * 16);
#pragma unroll
    for (int i = 0; i < 4; ++i)
      async_cp16(bP[i] + ko, smB + (i * 256 + tid) * 16);
    asm volatile("s_waitcnt vmcnt(0)" ::: "memory");
    __syncthreads();
#pragma unroll
    for (int s = 0; s < 2; ++s) {
      bf16x8 af[2], bfr[4];
#pragma unroll
      for (int mi = 0; mi < 2; ++mi) {
        int row = wm * 32 + mi * 16 + lm;
        af[mi] = *(const bf16x8*)(smA + row * 128 + (((s * 4 + q) ^ (lm & 7)) * 16));
      }
#pragma unroll
      for (int ni = 0; ni < 4; ++ni) {
        int row = wn * 64 + ni * 16 + lm;
        bfr[ni] = *(const bf16x8*)(smB + row * 128 + (((s * 4 + q) ^ (lm & 7)) * 16));
      }
#pragma unroll
      for (int mi = 0; mi < 2; ++mi)
#pragma unroll
        for (int ni = 0; ni < 4; ++ni)
          acc[mi][ni] = __builtin_amdgcn_mfma_f32_16x16x32_bf16(af[mi], bfr[ni], acc[mi][ni], 0, 0, 0);
    }
    __syncthreads();
  }

  // ---- fused SiLU epilogue: merged 64x64 u16 tile via LDS repack ----
  // acc[mi][2k] = gate, acc[mi][2k+1] = up for output col wn*32 + k*16 + lm.
  u16* smOut = (u16*)smB;  // [64][72] u16 (stride 72 for 16B-aligned rows)
#pragma unroll
  for (int mi = 0; mi < 2; ++mi) {
#pragma unroll
    for (int k = 0; k < 2; ++k) {
      int colL = wn * 32 + k * 16 + lm;
#pragma unroll
      for (int r = 0; r < 4; ++r) {
        float g = acc[mi][2 * k][r];
        float u = acc[mi][2 * k + 1][r];
        float a = g / (1.f + __expf(-g)) * u;
        int row = wm * 32 + mi * 16 + q * 4 + r;
        smOut[row * 72 + colL] = f2bf(a);
      }
    }
  }
  __syncthreads();
  {
    int row = tid >> 2, seg = tid & 3;           // seg = 16-u16 segment
    const u16* sp = smOut + row * 72 + seg * 16;
    bf16x8 v0 = *(const bf16x8*)sp;
    bf16x8 v1 = *(const bf16x8*)(sp + 8);
    u16* dp = Hb + ((size_t)e * CAP + m0 + row) * ID + (n0 >> 1) + seg * 16;
    *(bf16x8*)dp = v0;
    *(bf16x8*)(dp + 8) = v1;
  }
}

// ---------------- GEMM2: act . w2^T, fused combine (atomicAdd), 64x64 tile ----
// 4 waves (2x2 of 32x32), BK=64, 1024 active blocks (4/CU), 16 KB LDS.
__global__ __launch_bounds__(256) void gemm2_kernel(
    const u16* __restrict__ A, const u16* __restrict__ B, float* __restrict__ out,
    const int* __restrict__ rowmap, const int* __restrict__ counts,
    const float* __restrict__ tw) {
  int e = blockIdx.x;
  int count = counts[e];
  int m0 = blockIdx.y * 64;
  if (m0 >= count) return;
  int n0 = blockIdx.z * 64;
  int tid = threadIdx.x;
  int lane = tid & 63, wid = tid >> 6;
  int wm = wid >> 1, wn = wid & 1;
  int q = lane >> 4, lm = lane & 15;

  __shared__ __align__(16) char smA[64 * 128];  // 8 KB
  __shared__ __align__(16) char smB[64 * 128];  // 8 KB

  int rloc = tid >> 3;
  int chs = ((tid & 7) ^ (rloc & 7)) * 8;
  const u16* aP[2];
  const u16* bP[2];
#pragma unroll
  for (int i = 0; i < 2; ++i) {
    aP[i] = A + ((size_t)e * CAP + m0 + rloc + 32 * i) * ID + chs;
    bP[i] = B + ((size_t)e * HD + n0 + rloc + 32 * i) * ID + chs;
  }

  f32x4 zero = {0.f, 0.f, 0.f, 0.f};
  f32x4 acc[2][2];
#pragma unroll
  for (int mi = 0; mi < 2; ++mi)
#pragma unroll
    for (int ni = 0; ni < 2; ++ni) acc[mi][ni] = zero;

  for (int kt = 0; kt < ID / 64; ++kt) {
    int ko = kt * 64;
#pragma unroll
    for (int i = 0; i < 2; ++i) {
      async_cp16(aP[i] + ko, smA + (i * 256 + tid) * 16);
      async_cp16(bP[i] + ko, smB + (i * 256 + tid) * 16);
    }
    asm volatile("s_waitcnt vmcnt(0)" ::: "memory");
    __syncthreads();
#pragma unroll
    for (int s = 0; s < 2; ++s) {
      bf16x8 af[2], bfr[2];
#pragma unroll
      for (int mi = 0; mi < 2; ++mi) {
        int row = wm * 32 + mi * 16 + lm;
        af[mi] = *(const bf16x8*)(smA + row * 128 + (((s * 4 + q) ^ (lm & 7)) * 16));
      }
#pragma unroll
      for (int ni = 0; ni < 2; ++ni) {
        int row = wn * 32 + ni * 16 + lm;
        bfr[ni] = *(const bf16x8*)(smB + row * 128 + (((s * 4 + q) ^ (lm & 7)) * 16));
      }
#pragma unroll
      for (int mi = 0; mi < 2; ++mi)
#pragma unroll
        for (int ni = 0; ni < 2; ++ni)
          acc[mi][ni] = __builtin_amdgcn_mfma_f32_16x16x32_bf16(af[mi], bfr[ni], acc[mi][ni], 0, 0, 0);
    }
    __syncthreads();
  }

  // fused combine epilogue: out[token, col] += w * y
#pragma unroll
  for (int mi = 0; mi < 2; ++mi) {
#pragma unroll
    for (int r = 0; r < 4; ++r) {
      int grow = m0 + wm * 32 + mi * 16 + q * 4 + r;
      if (grow < count) {
        int f = rowmap[e * CAP + grow];
        float w = tw[f];
        int t = f >> 1;
#pragma unroll
        for (int ni = 0; ni < 2; ++ni) {
          int col = n0 + wn * 32 + ni * 16 + lm;
          atomicAdd(&out[(size_t)t * HD + col], w * acc[mi][ni][r]);
        }
      }
    }
  }
}

extern "C" void kernel_launch(void* const* d_in, const int* in_sizes, int n_in,
                              void* d_out, int out_size, void* d_ws, size_t ws_size,
                              hipStream_t stream) {
  const float* hidden = (const float*)d_in[0];
  const float* w1 = (const float*)d_in[1];
  const float* w2 = (const float*)d_in[2];
  const float* tw = (const float*)d_in[3];
  const int* ids = (const int*)d_in[4];
  float* out = (float*)d_out;

  char* p = (char*)d_ws;
  auto alloc = [&](size_t b) { char* r = p; p += (b + 255) & ~(size_t)255; return r; };
  u16* bw1 = (u16*)alloc((size_t)NE * 2 * ID * HD * 2);   // 46.1 MB (interleaved rows)
  u16* bw2 = (u16*)alloc((size_t)NE * HD * ID * 2);        // 23.1 MB
  u16* bx = (u16*)alloc((size_t)TT * HD * 2);              // 4.2 MB
  u16* hbuf = (u16*)alloc((size_t)NE * CAP * ID * 2);      // 23.1 MB (act only)
  int* rowmap = (int*)alloc((size_t)NE * CAP * 4);
  int* flatpos = (int*)alloc((size_t)TT * 2 * 4);
  int* counts = (int*)alloc((size_t)NE * 4);

  cvt_w1_kernel<<<dim3(2 * ID, NE), 256, 0, stream>>>((const float4*)w1, (ushort4*)bw1);
  int n4w2 = NE * HD * ID / 4;
  cvt_kernel<<<(n4w2 + 255) / 256, 256, 0, stream>>>((const float4*)w2, (ushort4*)bw2, n4w2);
  int n4x = TT * HD / 4;
  cvt_kernel<<<(n4x + 255) / 256, 256, 0, stream>>>((const float4*)hidden, (ushort4*)bx, n4x);

  route_kernel<<<1, 256, 0, stream>>>(ids, rowmap, flatpos, counts);

  int n4o = TT * HD / 4;
  zero_kernel<<<(n4o + 255) / 256, 256, 0, stream>>>((float4*)out, n4o);

  // GEMM1 + SiLU: hbuf[e,c,0:1408] = silu(x.w1g^T) * (x.w1u^T)
  gemm1_kernel<<<dim3(NE, CAP / 64, 2 * ID / 128), 256, 0, stream>>>(
      bx, bw1, hbuf, rowmap, counts);

  // GEMM2 + combine: out[t,:] += w * (act . w2^T)
  gemm2_kernel<<<dim3(NE, CAP / 64, HD / 64), 256, 0, stream>>>(
      hbuf, bw2, out, rowmap, counts, tw);
}